// Round 7
// baseline (10080.885 us; speedup 1.0000x reference)
//
#include <hip/hip_runtime.h>

#define B     16
#define TENC  128
#define TDEC  100
#define IND   256
#define HID   256
#define OD    400
#define MD    80
#define LBUF  17
#define BD    336
#define BS    5712
#define BH    571
#define MH    40
#define NSLOT 117

// roles: 195 bulk (age 2..16 x 13 col-tiles) + 4 age-17 (pq cols only) + 16 consumers
#define NW    199
#define NBLK  (NW + B)     // 215 blocks <= 256 CUs -> co-resident

// workspace layout (float offsets)
#define OFF_U    0                 // 117*16*336 = 628992   u row-major
#define OFF_UT   628992            // 117*5376   = 628992   u transposed [slot][d][b]
#define OFF_PA   1257984           // 16*128*256 = 524288
#define OFF_MEM  1782272           // 100*16*80  = 128000
#define OFF_M    1910272           // 17*336*400 = 2284800
#define OFF_CO   4195072           // 400
#define OFF_W2T  4195472           // 336*572    = 192192
#define OFF_P    4387664           // 4*16*832   = 53248    atomic-add accum, 4-deep parity
#define OFF_FLG  4440912           // 1024 ints: wdone[0..198], cons at +256 (32x16)

#define RLX __ATOMIC_RELAXED
#define AGT __HIP_MEMORY_SCOPE_AGENT
#define SCLD(p)    __hip_atomic_load((p), RLX, AGT)
#define SCST(p,v)  __hip_atomic_store((p), (v), RLX, AGT)

__global__ __launch_bounds__(256) void k_init(float* __restrict__ ws) {
    int i = blockIdx.x*256 + threadIdx.x;
    if (i < 91392) ws[OFF_U + i] = 0.f;                       // u slots 0..16
    else if (i < 182784) ws[OFF_UT + (i - 91392)] = 0.f;      // uT slots 0..16
    else if (i < 183184) ws[OFF_CO + (i - 182784)] = 0.f;
    else if (i < 236432) ws[OFF_P + (i - 183184)] = 0.f;
    else if (i < 237456) ((int*)(ws + OFF_FLG))[i - 236432] = 0;
}

__global__ __launch_bounds__(256) void k_pa(const float* __restrict__ inputs,
        const float* __restrict__ wa, const float* __restrict__ ba,
        float* __restrict__ ws) {
    int bj = blockIdx.x;
    int tid = threadIdx.x;
    __shared__ float xin[IND];
    xin[tid] = inputs[bj*IND + tid];
    __syncthreads();
    float acc = ba[tid];
    #pragma unroll 4
    for (int i = 0; i < IND; i++) acc += xin[i]*wa[i*HID + tid];
    ws[OFF_PA + bj*HID + tid] = acc;
}

__global__ __launch_bounds__(128) void k_mem(const float* __restrict__ targets,
        const float* __restrict__ w1, const float* __restrict__ b1,
        const float* __restrict__ w2, const float* __restrict__ b2,
        float* __restrict__ ws) {
    int tb = blockIdx.x; int t = tb / B; int b = tb % B;
    int tid = threadIdx.x;
    __shared__ float xin[OD];
    __shared__ float hid[MH];
    for (int k = tid; k < OD; k += 128)
        xin[k] = (t == 0) ? 0.f : targets[(b*TDEC + (t-1))*OD + k];
    __syncthreads();
    if (tid < MH) {
        float a = b1[tid];
        for (int k = 0; k < OD; k++) a += xin[k]*w1[k*MH + tid];
        hid[tid] = fmaxf(a, 0.f);
    }
    __syncthreads();
    if (tid < MD) {
        float a = b2[tid];
        #pragma unroll
        for (int k = 0; k < MH; k++) a += hid[k]*w2[k*MD + tid];
        ws[OFF_MEM + (t*B + b)*MD + tid] = a;
    }
}

__global__ __launch_bounds__(256) void k_M(const float* __restrict__ scale_w,
        const float* __restrict__ out_w, float* __restrict__ ws) {
    int l  = blockIdx.x / 14;
    int d0 = (blockIdx.x % 14) * 24;
    int tid = threadIdx.x;
    __shared__ float sw[HID*24];
    for (int idx = tid; idx < HID*24; idx += 256) {
        int h = idx / 24, dl = idx % 24;
        sw[idx] = scale_w[h*BD + d0 + dl];
    }
    __syncthreads();
    int o0 = tid, o1 = tid + 256;
    bool v1 = o1 < OD;
    float a0[24], a1[24];
    #pragma unroll
    for (int i = 0; i < 24; i++) { a0[i] = 0.f; a1[i] = 0.f; }
    const float* owl = out_w + l*HID*OD;
    for (int h = 0; h < HID; h++) {
        float w0 = owl[h*OD + o0];
        float w1v = v1 ? owl[h*OD + o1] : 0.f;
        #pragma unroll
        for (int dl = 0; dl < 24; dl++) {
            float s = sw[h*24 + dl];
            a0[dl] += s*w0; a1[dl] += s*w1v;
        }
    }
    float* Mp = ws + OFF_M + l*BD*OD;
    for (int dl = 0; dl < 24; dl++) {
        Mp[(d0+dl)*OD + o0] = a0[dl];
        if (v1) Mp[(d0+dl)*OD + o1] = a1[dl];
    }
}

__global__ __launch_bounds__(256) void k_cout(const float* __restrict__ scale_b,
        const float* __restrict__ out_w, const float* __restrict__ out_b,
        float* __restrict__ ws) {
    int l = blockIdx.x; int tid = threadIdx.x;
    for (int p = 0; p < 2; p++) {
        int o = tid + p*256;
        if (o < OD) {
            float acc = (l == 0) ? out_b[o] : 0.f;
            for (int h = 0; h < HID; h++) acc += scale_b[h]*out_w[(l*HID + h)*OD + o];
            atomicAdd(&ws[OFF_CO + o], acc);
        }
    }
}

// w2T[dd][c] = bp_w2[c][dd], c padded to 572 with zeros
__global__ __launch_bounds__(256) void k_tr(const float* __restrict__ bp_w2,
        float* __restrict__ ws) {
    int i = blockIdx.x*256 + threadIdx.x;
    if (i < BD*572) {
        int dd = i / 572, c = i - 572*dd;
        ws[OFF_W2T + i] = (c < BH) ? bp_w2[c*BD + dd] : 0.f;
    }
}

// ---------------- persistent scan ----------------
__global__ __launch_bounds__(512, 2) void k_scan(
        const float* __restrict__ inputs, const float* __restrict__ wq,
        const float* __restrict__ w1g, const float* __restrict__ att_bq,
        const float* __restrict__ bp_b1, const float* __restrict__ bp_b2,
        const float* __restrict__ att_v,
        float* __restrict__ ws, float* __restrict__ attns) {
    __shared__ __align__(16) float smem[13568];
    int bid = blockIdx.x, tid = threadIdx.x;
    int* flg = (int*)(ws + OFF_FLG);

    if (bid < NW) {
        // ============ WORKER: age a contribution of u_{t-a} to P ============
        int a, ct;
        if (bid < 195) { a = 2 + bid/13; ct = bid % 13; }
        else           { a = 17; ct = bid - 195; }
        float* ulds = smem;            // 5376
        float* red  = smem + 5376;     // 8192
        int cp = tid & 31, kq = tid >> 5;      // 16 kq slots x 21 k
        int c0 = ct*64 + cp, c1 = c0 + 32;
        bool v1 = c1 < 827;
        float wA[21], wB[21];
        #pragma unroll
        for (int g = 0; g < 21; g++) {
            int d = kq*21 + g;
            int rq = (a-1)*336 + d;
            wA[g] = (c0 < 256) ? wq[rq*256 + c0]
                  : ((a <= 16) ? w1g[(a*336 + d)*BH + (c0-256)] : 0.f);
            wB[g] = (!v1) ? 0.f
                  : ((c1 < 256) ? wq[rq*256 + c1]
                  : ((a <= 16) ? w1g[(a*336 + d)*BH + (c1-256)] : 0.f));
        }
        for (int t = 0; t < TDEC; t++) {
            // RUN-AHEAD CLAMP: P[t&3] is 4-deep shared accumulator — cannot add
            // step t's partials until the consumer has consumed & re-zeroed the
            // previous use of this parity slot (step t-4). Round 6's missing
            // clamp let age>=5 workers race 13 steps ahead -> absmax 2.8e24.
            int s = t - a; int s2 = t - 4;
            if (s2 > s) s = s2;
            if (s >= 0) {
                for (;;) {
                    int p = 1;
                    if (tid < 16) p = (SCLD(&flg[256 + ((s&31)<<4) + tid]) >= s+1);
                    if (__syncthreads_count(p) == 512) break;
                    __builtin_amdgcn_s_sleep(2);
                }
            }
            // two-phase batched stage of uT slot (coalesced, conflict-free)
            {
                const float* src = ws + OFF_UT + (t + 17 - a)*5376;
                float r[11];
                #pragma unroll
                for (int j = 0; j < 10; j++) r[j] = SCLD(&src[tid + j*512]);
                if (tid < 256) r[10] = SCLD(&src[tid + 5120]);
                #pragma unroll
                for (int j = 0; j < 10; j++) ulds[tid + j*512] = r[j];
                if (tid < 256) ulds[tid + 5120] = r[10];
            }
            __syncthreads();
            float a0[16], a1[16];
            #pragma unroll
            for (int i = 0; i < 16; i++) { a0[i] = 0.f; a1[i] = 0.f; }
            #pragma unroll
            for (int g = 0; g < 21; g++) {
                int base = (kq*21 + g)*16;
                float4 u0 = *(const float4*)&ulds[base];
                float4 u1 = *(const float4*)&ulds[base+4];
                float4 u2 = *(const float4*)&ulds[base+8];
                float4 u3 = *(const float4*)&ulds[base+12];
                float wa = wA[g], wb = wB[g];
                a0[0]=fmaf(wa,u0.x,a0[0]);  a1[0]=fmaf(wb,u0.x,a1[0]);
                a0[1]=fmaf(wa,u0.y,a0[1]);  a1[1]=fmaf(wb,u0.y,a1[1]);
                a0[2]=fmaf(wa,u0.z,a0[2]);  a1[2]=fmaf(wb,u0.z,a1[2]);
                a0[3]=fmaf(wa,u0.w,a0[3]);  a1[3]=fmaf(wb,u0.w,a1[3]);
                a0[4]=fmaf(wa,u1.x,a0[4]);  a1[4]=fmaf(wb,u1.x,a1[4]);
                a0[5]=fmaf(wa,u1.y,a0[5]);  a1[5]=fmaf(wb,u1.y,a1[5]);
                a0[6]=fmaf(wa,u1.z,a0[6]);  a1[6]=fmaf(wb,u1.z,a1[6]);
                a0[7]=fmaf(wa,u1.w,a0[7]);  a1[7]=fmaf(wb,u1.w,a1[7]);
                a0[8]=fmaf(wa,u2.x,a0[8]);  a1[8]=fmaf(wb,u2.x,a1[8]);
                a0[9]=fmaf(wa,u2.y,a0[9]);  a1[9]=fmaf(wb,u2.y,a1[9]);
                a0[10]=fmaf(wa,u2.z,a0[10]); a1[10]=fmaf(wb,u2.z,a1[10]);
                a0[11]=fmaf(wa,u2.w,a0[11]); a1[11]=fmaf(wb,u2.w,a1[11]);
                a0[12]=fmaf(wa,u3.x,a0[12]); a1[12]=fmaf(wb,u3.x,a1[12]);
                a0[13]=fmaf(wa,u3.y,a0[13]); a1[13]=fmaf(wb,u3.y,a1[13]);
                a0[14]=fmaf(wa,u3.z,a0[14]); a1[14]=fmaf(wb,u3.z,a1[14]);
                a0[15]=fmaf(wa,u3.w,a0[15]); a1[15]=fmaf(wb,u3.w,a1[15]);
            }
            if (kq < 8) {
                #pragma unroll
                for (int bb = 0; bb < 16; bb++) {
                    red[kq*1024 + bb*64 + cp]      = a0[bb];
                    red[kq*1024 + bb*64 + cp + 32] = a1[bb];
                }
            }
            __syncthreads();
            if (kq >= 8) {
                #pragma unroll
                for (int bb = 0; bb < 16; bb++) {
                    red[(kq-8)*1024 + bb*64 + cp]      += a0[bb];
                    red[(kq-8)*1024 + bb*64 + cp + 32] += a1[bb];
                }
            }
            __syncthreads();
            int par = t & 3;
            for (int oi = tid; oi < 1024; oi += 512) {
                float s_ = 0.f;
                #pragma unroll
                for (int q = 0; q < 8; q++) s_ += red[q*1024 + oi];
                int bb = oi >> 6, cl = oi & 63;
                __hip_atomic_fetch_add(
                    &ws[OFF_P + ((par*B + bb)*832) + ct*64 + cl], s_, RLX, AGT);
            }
            __syncthreads();                 // drains vmcnt(0) for the atomics
            if (tid == 0) SCST(&flg[bid], t + 1);
        }
    } else {
        // ============ CONSUMER (one per b): age1 + attention + top + h1 + u ===
        int b = bid - NW;
        float* uprev  = smem;          // 336
        float* pqa    = smem + 336;    // 832
        float* sc     = smem + 1168;   // 128
        float* attn_s = smem + 1296;   // 128
        float* ctx2   = smem + 1424;   // 512
        float* topv   = smem + 1936;   // 336
        float* h1     = smem + 2272;   // 576 (16B aligned)
        float* avs    = smem + 2848;   // 256
        for (int i = tid; i < 336; i += 512) uprev[i] = 0.f;
        if (tid < 256) avs[tid] = att_v[tid];
        if (tid == 0) h1[571] = 0.f;
        __syncthreads();
        for (int t = 0; t < TDEC; t++) {
            // Phase A: age-1 contribution (u_{t-1} is in uprev LDS)
            int c0 = tid;
            bool hasB = tid < 315;
            int c1 = tid + 512;
            float accA = 0.f, accB = 0.f;
            {
                const float* wAp; int strA;
                if (c0 < 256) { wAp = wq + c0;                    strA = 256; }
                else          { wAp = w1g + 336*BH + (c0-256);    strA = BH;  }
                const float* wBp = w1g + 336*BH + (c1-256);
                #pragma unroll 16
                for (int d = 0; d < 336; d++) {
                    float u = uprev[d];
                    accA = fmaf(u, wAp[d*strA], accA);
                    if (hasB) accB = fmaf(u, wBp[d*BH], accB);
                }
            }
            // Phase B: wait workers, add P + bias, zero P
            for (;;) {
                int p = 1;
                if (tid < NW) p = (SCLD(&flg[tid]) >= t+1);
                if (__syncthreads_count(p) == 512) break;
                __builtin_amdgcn_s_sleep(2);
            }
            {
                int par = t & 3;
                float* Pb = ws + OFF_P + (par*B + b)*832;
                float p0 = SCLD(&Pb[c0]);
                pqa[c0] = accA + p0 + (c0 < 256 ? att_bq[c0] : bp_b1[c0-256]);
                SCST(&Pb[c0], 0.f);
                if (hasB) {
                    float p1 = SCLD(&Pb[c1]);
                    pqa[c1] = accB + p1 + bp_b1[c1-256];
                    SCST(&Pb[c1], 0.f);
                }
                if (tid < 320 && !(tid < 315)) SCST(&Pb[tid + 512], 0.f);
            }
            __syncthreads();
            // Phase C: attention
            {
                int j = tid >> 2, hq = tid & 3;
                const float* par_ = ws + OFF_PA + (b*TENC + j)*HID + hq*64;
                const float* pqh = &pqa[hq*64];
                const float* avh = &avs[hq*64];
                float a = 0.f;
                #pragma unroll 8
                for (int h = 0; h < 64; h++) {
                    float x = pqh[h] + par_[h];
                    float e = __expf(2.f*x);
                    a += avh[h]*(1.f - 2.f/(e + 1.f));
                }
                a += __shfl_xor(a, 1);
                a += __shfl_xor(a, 2);
                if (hq == 0) sc[j] = a;
            }
            __syncthreads();
            if (tid < 64) {
                float s0 = sc[2*tid], s1 = sc[2*tid+1];
                float m = fmaxf(s0, s1);
                #pragma unroll
                for (int off = 1; off < 64; off <<= 1) m = fmaxf(m, __shfl_xor(m, off));
                float e0 = __expf(s0 - m), e1 = __expf(s1 - m);
                float ssum = e0 + e1;
                #pragma unroll
                for (int off = 1; off < 64; off <<= 1) ssum += __shfl_xor(ssum, off);
                float r = 1.f/ssum;
                attn_s[2*tid] = e0*r; attn_s[2*tid+1] = e1*r;
                attns[(b*TDEC + t)*TENC + 2*tid]   = e0*r;
                attns[(b*TDEC + t)*TENC + 2*tid+1] = e1*r;
            }
            __syncthreads();
            {   // ctx
                int i = tid & 255, jh = tid >> 8;
                const float* inp = inputs + (b*TENC + jh*64)*IND + i;
                float csum = 0.f;
                #pragma unroll 8
                for (int j = 0; j < 64; j++)
                    csum += attn_s[jh*64 + j]*inp[j*IND];
                ctx2[jh*256 + i] = csum;
            }
            __syncthreads();
            if (tid < 256) topv[tid] = ctx2[tid] + ctx2[256 + tid];
            else if (tid < BD) topv[tid] = ws[OFF_MEM + (t*B + b)*MD + (tid-256)];
            __syncthreads();
            // Phase D: top-row GEMV -> h1
            {
                float acc = 0.f;
                const float* wp = w1g + tid;
                #pragma unroll 16
                for (int d = 0; d < 336; d++) acc = fmaf(topv[d], wp[d*BH], acc);
                h1[tid] = fmaxf(pqa[256 + tid] + acc, 0.f);
                if (tid < 59) {
                    int c2 = tid + 512;
                    float acc2 = 0.f;
                    const float* wp2 = w1g + c2;
                    #pragma unroll 16
                    for (int d = 0; d < 336; d++) acc2 = fmaf(topv[d], wp2[d*BH], acc2);
                    h1[c2] = fmaxf(pqa[256 + c2] + acc2, 0.f);
                }
            }
            __syncthreads();
            // Phase E: u = b2 + h1 @ w2T ; publish u (row + transposed) + uprev
            if (tid < BD) {
                float v = bp_b2[tid];
                const float4* wp = (const float4*)(ws + OFF_W2T + tid*572);
                const float4* h4 = (const float4*)h1;
                #pragma unroll 13
                for (int q = 0; q < 143; q++) {
                    float4 w4 = wp[q], hh = h4[q];
                    v = fmaf(w4.x, hh.x, v); v = fmaf(w4.y, hh.y, v);
                    v = fmaf(w4.z, hh.z, v); v = fmaf(w4.w, hh.w, v);
                }
                SCST(&ws[OFF_U + (((t+17)*B + b)*BD) + tid], v);
                SCST(&ws[OFF_UT + (t+17)*5376 + tid*16 + b], v);
                uprev[tid] = v;
            }
            __syncthreads();                 // drains vmcnt(0)
            if (tid == 0) SCST(&flg[256 + ((t&31)<<4) + b], t + 1);
        }
    }
}

// Epilogue: out[b,t,o] = c_out[o] + sum_{l,d} u_{t-l}[b][d]*M[l][d][o]
__global__ __launch_bounds__(256) void k_q2(float* __restrict__ outs,
        const float* __restrict__ ws) {
    __shared__ __align__(16) float uL[41*340];
    int bid = blockIdx.x;
    int b = bid >> 5, r = bid & 31, th = r >> 3, oc = r & 7;
    int t0 = th*25, obase = oc*50;
    int tid = threadIdx.x;
    int s0 = t0 + 1;
    for (int idx = tid; idx < 41*336; idx += 256) {
        int rr = idx / 336, d = idx - 336*rr;
        uL[rr*340 + d] = ws[OFF_U + ((s0 + rr)*B + b)*BD + d];
    }
    __syncthreads();
    int o = tid % 50, tq = tid / 50;
    if (tq < 5) {
        float acc[5] = {0.f, 0.f, 0.f, 0.f, 0.f};
        for (int l = 0; l < LBUF; l++) {
            const float* Mp = ws + OFF_M + (l*BD)*OD + obase + o;
            const float* ub = &uL[(tq*5 + 16 - l)*340];
            for (int d4 = 0; d4 < 84; d4++) {
                int d = d4*4;
                float m0 = Mp[(d+0)*OD], m1 = Mp[(d+1)*OD];
                float m2 = Mp[(d+2)*OD], m3 = Mp[(d+3)*OD];
                #pragma unroll
                for (int i = 0; i < 5; i++) {
                    float4 u4 = *(const float4*)&ub[i*340 + d];
                    acc[i] = fmaf(u4.x, m0, acc[i]);
                    acc[i] = fmaf(u4.y, m1, acc[i]);
                    acc[i] = fmaf(u4.z, m2, acc[i]);
                    acc[i] = fmaf(u4.w, m3, acc[i]);
                }
            }
        }
        float co = ws[OFF_CO + obase + o];
        #pragma unroll
        for (int i = 0; i < 5; i++) {
            int t = t0 + tq*5 + i;
            outs[(b*TDEC + t)*OD + obase + o] = acc[i] + co;
        }
    }
}

extern "C" void kernel_launch(void* const* d_in, const int* in_sizes, int n_in,
                              void* d_out, int out_size, void* d_ws, size_t ws_size,
                              hipStream_t stream) {
    const float* inputs  = (const float*)d_in[0];
    const float* targets = (const float*)d_in[1];
    const float* mp_w1   = (const float*)d_in[2];
    const float* mp_b1   = (const float*)d_in[3];
    const float* mp_w2   = (const float*)d_in[4];
    const float* mp_b2   = (const float*)d_in[5];
    const float* bp_w1   = (const float*)d_in[6];
    const float* bp_b1   = (const float*)d_in[7];
    const float* bp_w2   = (const float*)d_in[8];
    const float* bp_b2   = (const float*)d_in[9];
    const float* att_wq  = (const float*)d_in[10];
    const float* att_bq  = (const float*)d_in[11];
    const float* att_wa  = (const float*)d_in[12];
    const float* att_ba  = (const float*)d_in[13];
    const float* att_v   = (const float*)d_in[14];
    const float* scale_w = (const float*)d_in[15];
    const float* scale_b = (const float*)d_in[16];
    const float* out_w   = (const float*)d_in[17];
    const float* out_b   = (const float*)d_in[18];
    float* ws = (float*)d_ws;
    float* outs = (float*)d_out;
    float* attns = outs + B*TDEC*OD;

    k_init<<<928, 256, 0, stream>>>(ws);
    k_pa  <<<B*TENC, 256, 0, stream>>>(inputs, att_wa, att_ba, ws);
    k_mem <<<TDEC*B, 128, 0, stream>>>(targets, mp_w1, mp_b1, mp_w2, mp_b2, ws);
    k_M   <<<17*14, 256, 0, stream>>>(scale_w, out_w, ws);
    k_cout<<<17, 256, 0, stream>>>(scale_b, out_w, out_b, ws);
    k_tr  <<<(BD*572 + 255)/256, 256, 0, stream>>>(bp_w2, ws);
    k_scan<<<NBLK, 512, 0, stream>>>(inputs, att_wq, bp_w1, att_bq, bp_b1,
                                     bp_b2, att_v, ws, attns);
    k_q2  <<<512, 256, 0, stream>>>(outs, ws);
}

// Round 9
// 4177.324 us; speedup vs baseline: 2.4132x; 2.4132x over previous
//
#include <hip/hip_runtime.h>

#define B     16
#define TENC  128
#define TDEC  100
#define IND   256
#define HID   256
#define OD    400
#define MD    80
#define LBUF  17
#define BD    336
#define BS    5712
#define BH    571
#define MH    40
#define NSLOT 117

// roles: 117 A (13 age-1 solo tiles + 8 age-pairs x 13 tiles)
//        18 T (top GEMV, 32 cols) ; 28 U (u GEMV, 12 rows) ; 16 consumers
#define NA    117
#define NT    18
#define NU2   28
#define NC    16
#define NBLK  (NA+NT+NU2+NC)   // 179 <= 256 CUs -> co-resident

// workspace layout (float offsets)
#define OFF_U    0                 // 117*16*336 u row-major (slot s = u_{s-17})
#define OFF_UT   628992            // 117*5376  u transposed [slot][d*16+b]
#define OFF_PA   1257984           // 16*128*256
#define OFF_MEM  1782272           // 100*16*80
#define OFF_M    1910272           // 17*336*400
#define OFF_CO   4195072           // 400
#define OFF_W2T  4195472           // 336*572
#define OFF_P    4387664           // 4*16*832 atomic accum (parity 4)
#define OFF_TOPT 4440912           // 2*5376  top transposed [par][d*16+b]
#define OFF_H    4451664           // 2*9216  S-prime then h1 [par][c*16+b]
#define OFF_FLG  4470096           // 512 ints: AF[117]@0 CF@128 TF@160 UF@192

#define RLX __ATOMIC_RELAXED
#define AGT __HIP_MEMORY_SCOPE_AGENT
#define SCLD(p)    __hip_atomic_load((p), RLX, AGT)
#define SCST(p,v)  __hip_atomic_store((p), (v), RLX, AGT)

__global__ __launch_bounds__(256) void k_init(float* __restrict__ ws) {
    int i = blockIdx.x*256 + threadIdx.x;
    if (i < 91392) ws[OFF_U + i] = 0.f;
    else if (i < 182784) ws[OFF_UT + (i - 91392)] = 0.f;
    else if (i < 183184) ws[OFF_CO + (i - 182784)] = 0.f;
    else if (i < 236432) ws[OFF_P + (i - 183184)] = 0.f;
    else if (i < 236944) ((int*)(ws + OFF_FLG))[i - 236432] = 0;
}

__global__ __launch_bounds__(256) void k_pa(const float* __restrict__ inputs,
        const float* __restrict__ wa, const float* __restrict__ ba,
        float* __restrict__ ws) {
    int bj = blockIdx.x;
    int tid = threadIdx.x;
    __shared__ float xin[IND];
    xin[tid] = inputs[bj*IND + tid];
    __syncthreads();
    float acc = ba[tid];
    #pragma unroll 4
    for (int i = 0; i < IND; i++) acc += xin[i]*wa[i*HID + tid];
    ws[OFF_PA + bj*HID + tid] = acc;
}

__global__ __launch_bounds__(128) void k_mem(const float* __restrict__ targets,
        const float* __restrict__ w1, const float* __restrict__ b1,
        const float* __restrict__ w2, const float* __restrict__ b2,
        float* __restrict__ ws) {
    int tb = blockIdx.x; int t = tb / B; int b = tb % B;
    int tid = threadIdx.x;
    __shared__ float xin[OD];
    __shared__ float hid[MH];
    for (int k = tid; k < OD; k += 128)
        xin[k] = (t == 0) ? 0.f : targets[(b*TDEC + (t-1))*OD + k];
    __syncthreads();
    if (tid < MH) {
        float a = b1[tid];
        for (int k = 0; k < OD; k++) a += xin[k]*w1[k*MH + tid];
        hid[tid] = fmaxf(a, 0.f);
    }
    __syncthreads();
    if (tid < MD) {
        float a = b2[tid];
        #pragma unroll
        for (int k = 0; k < MH; k++) a += hid[k]*w2[k*MD + tid];
        ws[OFF_MEM + (t*B + b)*MD + tid] = a;
    }
}

__global__ __launch_bounds__(256) void k_M(const float* __restrict__ scale_w,
        const float* __restrict__ out_w, float* __restrict__ ws) {
    int l  = blockIdx.x / 14;
    int d0 = (blockIdx.x % 14) * 24;
    int tid = threadIdx.x;
    __shared__ float sw[HID*24];
    for (int idx = tid; idx < HID*24; idx += 256) {
        int h = idx / 24, dl = idx % 24;
        sw[idx] = scale_w[h*BD + d0 + dl];
    }
    __syncthreads();
    int o0 = tid, o1 = tid + 256;
    bool v1 = o1 < OD;
    float a0[24], a1[24];
    #pragma unroll
    for (int i = 0; i < 24; i++) { a0[i] = 0.f; a1[i] = 0.f; }
    const float* owl = out_w + l*HID*OD;
    for (int h = 0; h < HID; h++) {
        float w0 = owl[h*OD + o0];
        float w1v = v1 ? owl[h*OD + o1] : 0.f;
        #pragma unroll
        for (int dl = 0; dl < 24; dl++) {
            float s = sw[h*24 + dl];
            a0[dl] += s*w0; a1[dl] += s*w1v;
        }
    }
    float* Mp = ws + OFF_M + l*BD*OD;
    for (int dl = 0; dl < 24; dl++) {
        Mp[(d0+dl)*OD + o0] = a0[dl];
        if (v1) Mp[(d0+dl)*OD + o1] = a1[dl];
    }
}

__global__ __launch_bounds__(256) void k_cout(const float* __restrict__ scale_b,
        const float* __restrict__ out_w, const float* __restrict__ out_b,
        float* __restrict__ ws) {
    int l = blockIdx.x; int tid = threadIdx.x;
    for (int p = 0; p < 2; p++) {
        int o = tid + p*256;
        if (o < OD) {
            float acc = (l == 0) ? out_b[o] : 0.f;
            for (int h = 0; h < HID; h++) acc += scale_b[h]*out_w[(l*HID + h)*OD + o];
            atomicAdd(&ws[OFF_CO + o], acc);
        }
    }
}

__global__ __launch_bounds__(256) void k_tr(const float* __restrict__ bp_w2,
        float* __restrict__ ws) {
    int i = blockIdx.x*256 + threadIdx.x;
    if (i < BD*572) {
        int dd = i / 572, c = i - 572*dd;
        ws[OFF_W2T + i] = (c < BH) ? bp_w2[c*BD + dd] : 0.f;
    }
}

// ---------------- persistent scan ----------------
// Chain per step: UF[t-1] -> A(age1) -> consumer(attn) -> T -> U -> UF[t].
// T and U use SINGLE-ACCUMULATOR SERIAL summation (R7 bracketing — the
// 16-way trees of round 8 shifted the trajectory past the bf16 threshold).
__global__ __launch_bounds__(512) void k_scan(
        const float* __restrict__ inputs, const float* __restrict__ wq,
        const float* __restrict__ w1g, const float* __restrict__ att_bq,
        const float* __restrict__ bp_b1, const float* __restrict__ bp_b2,
        const float* __restrict__ att_v,
        float* __restrict__ ws, float* __restrict__ attns) {
    __shared__ __align__(16) float smem[16128];   // 63 KB
    int bid = blockIdx.x, tid = threadIdx.x;
    int* AF = (int*)(ws + OFF_FLG);
    int* CF = AF + 128;
    int* TF = AF + 160;
    int* UF = AF + 192;

    if (bid < NA) {
        // ====== A-WORKER: ages a_lo..a_lo+n_ages-1 contribution to P ======
        int a_lo, n_ages, ct;
        if (bid < 13) { a_lo = 1; n_ages = 1; ct = bid; }
        else { int q = bid - 13; int p = q/13; ct = q - 13*p; a_lo = 2 + 2*p; n_ages = 2; }
        float* ulds = smem;            // 5376
        float* red  = smem + 5376;     // 8192
        int cp = tid & 31, kq = tid >> 5;
        int c0 = ct*64 + cp, c1 = c0 + 32;
        float wA[2][21], wB[2][21];
        for (int ia = 0; ia < 2; ia++) {
            int a = a_lo + ia;
            #pragma unroll
            for (int g = 0; g < 21; g++) {
                int d = kq*21 + g;
                float va = 0.f, vb = 0.f;
                if (ia < n_ages) {
                    va = (c0 < 256) ? wq[((a-1)*336+d)*256 + c0]
                       : ((a <= 16 && c0 < 827) ? w1g[(a*336+d)*BH + (c0-256)] : 0.f);
                    vb = (c1 < 256) ? wq[((a-1)*336+d)*256 + c1]
                       : ((a <= 16 && c1 < 827) ? w1g[(a*336+d)*BH + (c1-256)] : 0.f);
                }
                wA[ia][g] = va; wB[ia][g] = vb;
            }
        }
        int aw = (a_lo < 4) ? a_lo : 4;   // P[t&3] freed by consumer t-4 (UF chain)
        for (int t = 0; t < TDEC; t++) {
            int s = t - aw;
            if (s >= 0) {
                for (;;) {
                    int p = 1;
                    if (tid < NU2) p = (SCLD(&UF[tid]) >= s+1);
                    if (__syncthreads_count(p) == 512) break;
                    __builtin_amdgcn_s_sleep(1);
                }
            }
            float a0[16], a1[16];
            #pragma unroll
            for (int i = 0; i < 16; i++) { a0[i] = 0.f; a1[i] = 0.f; }
            for (int ia = 0; ia < n_ages; ia++) {
                int a = a_lo + ia;
                if (ia) __syncthreads();
                {   // batched stage of uT slot t+17-a (u_{t-a})
                    const float* src = ws + OFF_UT + (t + 17 - a)*5376;
                    float r[11];
                    #pragma unroll
                    for (int j = 0; j < 10; j++) r[j] = SCLD(&src[tid + j*512]);
                    if (tid < 256) r[10] = SCLD(&src[tid + 5120]);
                    #pragma unroll
                    for (int j = 0; j < 10; j++) ulds[tid + j*512] = r[j];
                    if (tid < 256) ulds[tid + 5120] = r[10];
                }
                __syncthreads();
                #pragma unroll
                for (int g = 0; g < 21; g++) {
                    int base = (kq*21 + g)*16;
                    float4 u0 = *(const float4*)&ulds[base];
                    float4 u1 = *(const float4*)&ulds[base+4];
                    float4 u2 = *(const float4*)&ulds[base+8];
                    float4 u3 = *(const float4*)&ulds[base+12];
                    float wa = wA[ia][g], wb = wB[ia][g];
                    a0[0]=fmaf(wa,u0.x,a0[0]);  a1[0]=fmaf(wb,u0.x,a1[0]);
                    a0[1]=fmaf(wa,u0.y,a0[1]);  a1[1]=fmaf(wb,u0.y,a1[1]);
                    a0[2]=fmaf(wa,u0.z,a0[2]);  a1[2]=fmaf(wb,u0.z,a1[2]);
                    a0[3]=fmaf(wa,u0.w,a0[3]);  a1[3]=fmaf(wb,u0.w,a1[3]);
                    a0[4]=fmaf(wa,u1.x,a0[4]);  a1[4]=fmaf(wb,u1.x,a1[4]);
                    a0[5]=fmaf(wa,u1.y,a0[5]);  a1[5]=fmaf(wb,u1.y,a1[5]);
                    a0[6]=fmaf(wa,u1.z,a0[6]);  a1[6]=fmaf(wb,u1.z,a1[6]);
                    a0[7]=fmaf(wa,u1.w,a0[7]);  a1[7]=fmaf(wb,u1.w,a1[7]);
                    a0[8]=fmaf(wa,u2.x,a0[8]);  a1[8]=fmaf(wb,u2.x,a1[8]);
                    a0[9]=fmaf(wa,u2.y,a0[9]);  a1[9]=fmaf(wb,u2.y,a1[9]);
                    a0[10]=fmaf(wa,u2.z,a0[10]); a1[10]=fmaf(wb,u2.z,a1[10]);
                    a0[11]=fmaf(wa,u2.w,a0[11]); a1[11]=fmaf(wb,u2.w,a1[11]);
                    a0[12]=fmaf(wa,u3.x,a0[12]); a1[12]=fmaf(wb,u3.x,a1[12]);
                    a0[13]=fmaf(wa,u3.y,a0[13]); a1[13]=fmaf(wb,u3.y,a1[13]);
                    a0[14]=fmaf(wa,u3.z,a0[14]); a1[14]=fmaf(wb,u3.z,a1[14]);
                    a0[15]=fmaf(wa,u3.w,a0[15]); a1[15]=fmaf(wb,u3.w,a1[15]);
                }
            }
            if (kq < 8) {
                #pragma unroll
                for (int bb = 0; bb < 16; bb++) {
                    red[kq*1024 + bb*64 + cp]      = a0[bb];
                    red[kq*1024 + bb*64 + cp + 32] = a1[bb];
                }
            }
            __syncthreads();
            if (kq >= 8) {
                #pragma unroll
                for (int bb = 0; bb < 16; bb++) {
                    red[(kq-8)*1024 + bb*64 + cp]      += a0[bb];
                    red[(kq-8)*1024 + bb*64 + cp + 32] += a1[bb];
                }
            }
            __syncthreads();
            int par = t & 3;
            for (int oi = tid; oi < 1024; oi += 512) {
                float s_ = 0.f;
                #pragma unroll
                for (int q = 0; q < 8; q++) s_ += red[q*1024 + oi];
                int bb = oi >> 6, cl = oi & 63;
                __hip_atomic_fetch_add(
                    &ws[OFF_P + ((par*B + bb)*832) + ct*64 + cl], s_, RLX, AGT);
            }
            __syncthreads();
            if (tid == 0) SCST(&AF[bid], t + 1);
        }
    } else if (bid < NA + NT) {
        // ====== T-WORKER: h1[col][b] = relu(prime + sum_d top[b][d]*w1[d][col]) ==
        int f = bid - NA;
        float* w1L  = smem;            // 336*32 = 10752
        float* tlds = smem + 10752;    // 5376
        for (int idx = tid; idx < 10752; idx += 512) {
            int d = idx >> 5, c = idx & 31;
            int col = f*32 + c;
            w1L[idx] = (col < BH) ? w1g[d*BH + col] : 0.f;
        }
        __syncthreads();
        int cl = tid >> 4, b = tid & 15;
        int col = f*32 + cl;
        for (int t = 0; t < TDEC; t++) {
            for (;;) {
                int p = 1;
                if (tid < NC) p = (SCLD(&CF[tid]) >= t+1);
                if (__syncthreads_count(p) == 512) break;
                __builtin_amdgcn_s_sleep(1);
            }
            int par2 = t & 1;
            float prime = SCLD(&ws[OFF_H + par2*9216 + f*512 + tid]);
            {   // batched stage of topT[par2]
                const float* src = ws + OFF_TOPT + par2*5376;
                float r[11];
                #pragma unroll
                for (int j = 0; j < 10; j++) r[j] = SCLD(&src[tid + j*512]);
                if (tid < 256) r[10] = SCLD(&src[tid + 5120]);
                #pragma unroll
                for (int j = 0; j < 10; j++) tlds[tid + j*512] = r[j];
                if (tid < 256) tlds[tid + 5120] = r[10];
            }
            __syncthreads();
            float acc = 0.f;                 // single-accumulator serial (R7 order)
            const float* wrow = w1L + cl;
            const float* trow = tlds + b;
            #pragma unroll 8
            for (int d = 0; d < 336; d++)
                acc = fmaf(trow[d*16], wrow[d*32], acc);
            if (col < BH)
                SCST(&ws[OFF_H + par2*9216 + f*512 + tid], fmaxf(prime + acc, 0.f));
            __syncthreads();
            if (tid == 0) SCST(&TF[f], t + 1);
        }
    } else if (bid < NA + NT + NU2) {
        // ====== U-WORKER: u[b][dd] = b2[dd] + sum_c h1[c][b]*w2T[dd][c] ======
        int ub = bid - (NA + NT);
        int dd0 = ub*12;
        float* w2L  = smem;            // 12*572 = 6864
        float* hlds = smem + 6864;     // 9136
        for (int idx = tid; idx < 6864; idx += 512)
            w2L[idx] = ws[OFF_W2T + dd0*572 + idx];
        __syncthreads();
        int ddl = tid >> 4, b = tid & 15;
        bool act = tid < 192;
        for (int t = 0; t < TDEC; t++) {
            for (;;) {
                int p = 1;
                if (tid < NT) p = (SCLD(&TF[tid]) >= t+1);
                if (__syncthreads_count(p) == 512) break;
                __builtin_amdgcn_s_sleep(1);
            }
            int par2 = t & 1;
            {   // batched stage of h1 (post-relu H), 9136 floats
                const float* src = ws + OFF_H + par2*9216;
                float r[18];
                #pragma unroll
                for (int j = 0; j < 18; j++) {
                    int idx = tid + j*512;
                    r[j] = (idx < 9136) ? SCLD(&src[idx]) : 0.f;
                }
                #pragma unroll
                for (int j = 0; j < 18; j++) {
                    int idx = tid + j*512;
                    if (idx < 9136) hlds[idx] = r[j];
                }
            }
            __syncthreads();
            if (act) {
                float v = bp_b2[dd0 + ddl];  // single-accumulator serial (R7 order)
                const float* wrow = w2L + ddl*572;
                const float* hrow = hlds + b;
                #pragma unroll 8
                for (int c = 0; c < BH; c++)
                    v = fmaf(hrow[c*16], wrow[c], v);
                SCST(&ws[OFF_U + ((t+17)*B + b)*BD + dd0 + ddl], v);
                SCST(&ws[OFF_UT + (t+17)*5376 + (dd0+ddl)*16 + b], v);
            }
            __syncthreads();
            if (tid == 0) SCST(&UF[ub], t + 1);
        }
    } else {
        // ====== CONSUMER (one per b): merge P + attention + publish ======
        int b = bid - (NA + NT + NU2);
        float* pqa    = smem;          // 832
        float* sc     = smem + 832;    // 128
        float* attn_s = smem + 960;    // 128
        float* ctx2   = smem + 1088;   // 512
        float* topv   = smem + 1600;   // 336
        float* avs    = smem + 1936;   // 256
        if (tid < 256) avs[tid] = att_v[tid];
        __syncthreads();
        for (int t = 0; t < TDEC; t++) {
            for (;;) {
                int p = 1;
                if (tid < NA) p = (SCLD(&AF[tid]) >= t+1);
                if (__syncthreads_count(p) == 512) break;
                __builtin_amdgcn_s_sleep(1);
            }
            int par3 = t & 3, par2 = t & 1;
            {   // merge P row, add biases, zero P
                float* Pb = ws + OFF_P + (par3*B + b)*832;
                int c0 = tid;
                float p0 = SCLD(&Pb[c0]);
                SCST(&Pb[c0], 0.f);
                pqa[c0] = p0 + (c0 < 256 ? att_bq[c0] : bp_b1[c0-256]);
                if (tid < 315) {
                    int c1 = tid + 512;
                    float p1 = SCLD(&Pb[c1]);
                    SCST(&Pb[c1], 0.f);
                    pqa[c1] = p1 + bp_b1[c1-256];
                }
            }
            __syncthreads();
            {   // scores
                int j = tid >> 2, hq = tid & 3;
                const float* par_ = ws + OFF_PA + (b*TENC + j)*HID + hq*64;
                const float* pqh = &pqa[hq*64];
                const float* avh = &avs[hq*64];
                float a = 0.f;
                #pragma unroll 8
                for (int h = 0; h < 64; h++) {
                    float x = pqh[h] + par_[h];
                    float e = __expf(2.f*x);
                    a += avh[h]*(1.f - 2.f/(e + 1.f));
                }
                a += __shfl_xor(a, 1);
                a += __shfl_xor(a, 2);
                if (hq == 0) sc[j] = a;
            }
            __syncthreads();
            if (tid < 64) {
                float s0 = sc[2*tid], s1 = sc[2*tid+1];
                float m = fmaxf(s0, s1);
                #pragma unroll
                for (int off = 1; off < 64; off <<= 1) m = fmaxf(m, __shfl_xor(m, off));
                float e0 = __expf(s0 - m), e1 = __expf(s1 - m);
                float ssum = e0 + e1;
                #pragma unroll
                for (int off = 1; off < 64; off <<= 1) ssum += __shfl_xor(ssum, off);
                float r = 1.f/ssum;
                attn_s[2*tid] = e0*r; attn_s[2*tid+1] = e1*r;
                attns[(b*TDEC + t)*TENC + 2*tid]   = e0*r;
                attns[(b*TDEC + t)*TENC + 2*tid+1] = e1*r;
            }
            __syncthreads();
            {   // ctx
                int i = tid & 255, jh = tid >> 8;
                const float* inp = inputs + (b*TENC + jh*64)*IND + i;
                float csum = 0.f;
                #pragma unroll 8
                for (int j = 0; j < 64; j++)
                    csum += attn_s[jh*64 + j]*inp[j*IND];
                ctx2[jh*256 + i] = csum;
            }
            __syncthreads();
            if (tid < 256) topv[tid] = ctx2[tid] + ctx2[256 + tid];
            else if (tid < BD) topv[tid] = ws[OFF_MEM + (t*B + b)*MD + (tid-256)];
            __syncthreads();
            // publish topT (transposed) + H prime (S partial incl bias)
            if (tid < BD)
                SCST(&ws[OFF_TOPT + par2*5376 + tid*16 + b], topv[tid]);
            SCST(&ws[OFF_H + par2*9216 + tid*16 + b], pqa[256 + tid]);
            if (tid < 59)
                SCST(&ws[OFF_H + par2*9216 + (tid+512)*16 + b], pqa[256 + tid + 512]);
            __syncthreads();
            if (tid == 0) SCST(&CF[b], t + 1);
        }
    }
}

// Epilogue: out[b,t,o] = c_out[o] + sum_{l,d} u_{t-l}[b][d]*M[l][d][o]
__global__ __launch_bounds__(256) void k_q2(float* __restrict__ outs,
        const float* __restrict__ ws) {
    __shared__ __align__(16) float uL[41*340];
    int bid = blockIdx.x;
    int b = bid >> 5, r = bid & 31, th = r >> 3, oc = r & 7;
    int t0 = th*25, obase = oc*50;
    int tid = threadIdx.x;
    int s0 = t0 + 1;
    for (int idx = tid; idx < 41*336; idx += 256) {
        int rr = idx / 336, d = idx - 336*rr;
        uL[rr*340 + d] = ws[OFF_U + ((s0 + rr)*B + b)*BD + d];
    }
    __syncthreads();
    int o = tid % 50, tq = tid / 50;
    if (tq < 5) {
        float acc[5] = {0.f, 0.f, 0.f, 0.f, 0.f};
        for (int l = 0; l < LBUF; l++) {
            const float* Mp = ws + OFF_M + (l*BD)*OD + obase + o;
            const float* ub = &uL[(tq*5 + 16 - l)*340];
            for (int d4 = 0; d4 < 84; d4++) {
                int d = d4*4;
                float m0 = Mp[(d+0)*OD], m1 = Mp[(d+1)*OD];
                float m2 = Mp[(d+2)*OD], m3 = Mp[(d+3)*OD];
                #pragma unroll
                for (int i = 0; i < 5; i++) {
                    float4 u4 = *(const float4*)&ub[i*340 + d];
                    acc[i] = fmaf(u4.x, m0, acc[i]);
                    acc[i] = fmaf(u4.y, m1, acc[i]);
                    acc[i] = fmaf(u4.z, m2, acc[i]);
                    acc[i] = fmaf(u4.w, m3, acc[i]);
                }
            }
        }
        float co = ws[OFF_CO + obase + o];
        #pragma unroll
        for (int i = 0; i < 5; i++) {
            int t = t0 + tq*5 + i;
            outs[(b*TDEC + t)*OD + obase + o] = acc[i] + co;
        }
    }
}

extern "C" void kernel_launch(void* const* d_in, const int* in_sizes, int n_in,
                              void* d_out, int out_size, void* d_ws, size_t ws_size,
                              hipStream_t stream) {
    const float* inputs  = (const float*)d_in[0];
    const float* targets = (const float*)d_in[1];
    const float* mp_w1   = (const float*)d_in[2];
    const float* mp_b1   = (const float*)d_in[3];
    const float* mp_w2   = (const float*)d_in[4];
    const float* mp_b2   = (const float*)d_in[5];
    const float* bp_w1   = (const float*)d_in[6];
    const float* bp_b1   = (const float*)d_in[7];
    const float* bp_w2   = (const float*)d_in[8];
    const float* bp_b2   = (const float*)d_in[9];
    const float* att_wq  = (const float*)d_in[10];
    const float* att_bq  = (const float*)d_in[11];
    const float* att_wa  = (const float*)d_in[12];
    const float* att_ba  = (const float*)d_in[13];
    const float* att_v   = (const float*)d_in[14];
    const float* scale_w = (const float*)d_in[15];
    const float* scale_b = (const float*)d_in[16];
    const float* out_w   = (const float*)d_in[17];
    const float* out_b   = (const float*)d_in[18];
    float* ws = (float*)d_ws;
    float* outs = (float*)d_out;
    float* attns = outs + B*TDEC*OD;

    k_init<<<926, 256, 0, stream>>>(ws);
    k_pa  <<<B*TENC, 256, 0, stream>>>(inputs, att_wa, att_ba, ws);
    k_mem <<<TDEC*B, 128, 0, stream>>>(targets, mp_w1, mp_b1, mp_w2, mp_b2, ws);
    k_M   <<<17*14, 256, 0, stream>>>(scale_w, out_w, ws);
    k_cout<<<17, 256, 0, stream>>>(scale_b, out_w, out_b, ws);
    k_tr  <<<(BD*572 + 255)/256, 256, 0, stream>>>(bp_w2, ws);
    k_scan<<<NBLK, 512, 0, stream>>>(inputs, att_wq, bp_w1, att_bq, bp_b1,
                                     bp_b2, att_v, ws, attns);
    k_q2  <<<512, 256, 0, stream>>>(outs, ws);
}

// Round 10
// 3522.339 us; speedup vs baseline: 2.8620x; 1.1860x over previous
//
#include <hip/hip_runtime.h>

#define B     16
#define TENC  128
#define TDEC  100
#define IND   256
#define HID   256
#define OD    400
#define MD    80
#define LBUF  17
#define BD    336
#define BS    5712
#define BH    571
#define MH    40
#define NSLOT 117

// roles: 117 A (13 age-1 solo tiles + 8 age-pairs x 13 tiles)
//        18 T (top GEMV, 32 cols) ; 28 U (u GEMV, 12 rows) ; 16 consumers
#define NA    117
#define NT    18
#define NU2   28
#define NC    16
#define NBLK  (NA+NT+NU2+NC)   // 179 <= 256 CUs -> co-resident

// workspace layout (float offsets)
#define OFF_U    0                 // 117*5376 u row-major [slot][b][336]
#define OFF_PA   628992            // 16*128*256
#define OFF_MEM  1153280           // 100*16*80
#define OFF_M    1281280           // 17*336*400
#define OFF_CO   3566080           // 400
#define OFF_W2T  3566480           // 336*572
#define OFF_P    3758672           // 4*16*832 atomic accum (parity 4)
#define OFF_TOP  3811920           // 2*16*336 top row-major [par][b][336]
#define OFF_H    3822672           // 2*16*572 S-prime then h1 [par][b][572]
#define OFF_FLG  3840976           // 512 ints: AF[117]@0 CF@128 TF@160 UF@192

#define RLX __ATOMIC_RELAXED
#define AGT __HIP_MEMORY_SCOPE_AGENT
#define SCLD(p)    __hip_atomic_load((p), RLX, AGT)
#define SCST(p,v)  __hip_atomic_store((p), (v), RLX, AGT)

__global__ __launch_bounds__(256) void k_init(float* __restrict__ ws) {
    int i = blockIdx.x*256 + threadIdx.x;
    if (i < 91392) ws[OFF_U + i] = 0.f;                  // u slots 0..16
    else if (i < 91792) ws[OFF_CO + (i - 91392)] = 0.f;
    else if (i < 145040) ws[OFF_P + (i - 91792)] = 0.f;
    else if (i < 145552) ((int*)(ws + OFF_FLG))[i - 145040] = 0;
}

__global__ __launch_bounds__(256) void k_pa(const float* __restrict__ inputs,
        const float* __restrict__ wa, const float* __restrict__ ba,
        float* __restrict__ ws) {
    int bj = blockIdx.x;
    int tid = threadIdx.x;
    __shared__ float xin[IND];
    xin[tid] = inputs[bj*IND + tid];
    __syncthreads();
    float acc = ba[tid];
    #pragma unroll 4
    for (int i = 0; i < IND; i++) acc += xin[i]*wa[i*HID + tid];
    ws[OFF_PA + bj*HID + tid] = acc;
}

__global__ __launch_bounds__(128) void k_mem(const float* __restrict__ targets,
        const float* __restrict__ w1, const float* __restrict__ b1,
        const float* __restrict__ w2, const float* __restrict__ b2,
        float* __restrict__ ws) {
    int tb = blockIdx.x; int t = tb / B; int b = tb % B;
    int tid = threadIdx.x;
    __shared__ float xin[OD];
    __shared__ float hid[MH];
    for (int k = tid; k < OD; k += 128)
        xin[k] = (t == 0) ? 0.f : targets[(b*TDEC + (t-1))*OD + k];
    __syncthreads();
    if (tid < MH) {
        float a = b1[tid];
        for (int k = 0; k < OD; k++) a += xin[k]*w1[k*MH + tid];
        hid[tid] = fmaxf(a, 0.f);
    }
    __syncthreads();
    if (tid < MD) {
        float a = b2[tid];
        #pragma unroll
        for (int k = 0; k < MH; k++) a += hid[k]*w2[k*MD + tid];
        ws[OFF_MEM + (t*B + b)*MD + tid] = a;
    }
}

__global__ __launch_bounds__(256) void k_M(const float* __restrict__ scale_w,
        const float* __restrict__ out_w, float* __restrict__ ws) {
    int l  = blockIdx.x / 14;
    int d0 = (blockIdx.x % 14) * 24;
    int tid = threadIdx.x;
    __shared__ float sw[HID*24];
    for (int idx = tid; idx < HID*24; idx += 256) {
        int h = idx / 24, dl = idx % 24;
        sw[idx] = scale_w[h*BD + d0 + dl];
    }
    __syncthreads();
    int o0 = tid, o1 = tid + 256;
    bool v1 = o1 < OD;
    float a0[24], a1[24];
    #pragma unroll
    for (int i = 0; i < 24; i++) { a0[i] = 0.f; a1[i] = 0.f; }
    const float* owl = out_w + l*HID*OD;
    for (int h = 0; h < HID; h++) {
        float w0 = owl[h*OD + o0];
        float w1v = v1 ? owl[h*OD + o1] : 0.f;
        #pragma unroll
        for (int dl = 0; dl < 24; dl++) {
            float s = sw[h*24 + dl];
            a0[dl] += s*w0; a1[dl] += s*w1v;
        }
    }
    float* Mp = ws + OFF_M + l*BD*OD;
    for (int dl = 0; dl < 24; dl++) {
        Mp[(d0+dl)*OD + o0] = a0[dl];
        if (v1) Mp[(d0+dl)*OD + o1] = a1[dl];
    }
}

__global__ __launch_bounds__(256) void k_cout(const float* __restrict__ scale_b,
        const float* __restrict__ out_w, const float* __restrict__ out_b,
        float* __restrict__ ws) {
    int l = blockIdx.x; int tid = threadIdx.x;
    for (int p = 0; p < 2; p++) {
        int o = tid + p*256;
        if (o < OD) {
            float acc = (l == 0) ? out_b[o] : 0.f;
            for (int h = 0; h < HID; h++) acc += scale_b[h]*out_w[(l*HID + h)*OD + o];
            atomicAdd(&ws[OFF_CO + o], acc);
        }
    }
}

__global__ __launch_bounds__(256) void k_tr(const float* __restrict__ bp_w2,
        float* __restrict__ ws) {
    int i = blockIdx.x*256 + threadIdx.x;
    if (i < BD*572) {
        int dd = i / 572, c = i - 572*dd;
        ws[OFF_W2T + i] = (c < BH) ? bp_w2[c*BD + dd] : 0.f;
    }
}

// ---------------- persistent scan ----------------
// Chain per step: UF[t-1] -> A(age1) -> consumer(attn) -> T -> U -> UF[t].
// T and U keep the R7/R9 single-accumulator serial bracket; float4 loads are
// in-order FMA chains = bit-identical arithmetic. Publishes are coalesced.
__global__ __launch_bounds__(512) void k_scan(
        const float* __restrict__ inputs, const float* __restrict__ wq,
        const float* __restrict__ w1g, const float* __restrict__ att_bq,
        const float* __restrict__ bp_b1, const float* __restrict__ bp_b2,
        const float* __restrict__ att_v,
        float* __restrict__ ws, float* __restrict__ attns) {
    __shared__ __align__(16) float smem[16192];   // 63.25 KB
    int bid = blockIdx.x, tid = threadIdx.x;
    int* AF = (int*)(ws + OFF_FLG);
    int* CF = AF + 128;
    int* TF = AF + 160;
    int* UF = AF + 192;

    if (bid < NA) {
        // ====== A-WORKER: ages a_lo..a_lo+n_ages-1 contribution to P ======
        int a_lo, n_ages, ct;
        if (bid < 13) { a_lo = 1; n_ages = 1; ct = bid; }
        else { int q = bid - 13; int p = q/13; ct = q - 13*p; a_lo = 2 + 2*p; n_ages = 2; }
        float* ulds = smem;            // 336*20 = 6720 [d*20 + b]
        float* red  = smem + 6720;     // 8192
        int cp = tid & 31, kq = tid >> 5;
        int c0 = ct*64 + cp, c1 = c0 + 32;
        float wA[2][21], wB[2][21];
        for (int ia = 0; ia < 2; ia++) {
            int a = a_lo + ia;
            #pragma unroll
            for (int g = 0; g < 21; g++) {
                int d = kq*21 + g;
                float va = 0.f, vb = 0.f;
                if (ia < n_ages) {
                    va = (c0 < 256) ? wq[((a-1)*336+d)*256 + c0]
                       : ((a <= 16 && c0 < 827) ? w1g[(a*336+d)*BH + (c0-256)] : 0.f);
                    vb = (c1 < 256) ? wq[((a-1)*336+d)*256 + c1]
                       : ((a <= 16 && c1 < 827) ? w1g[(a*336+d)*BH + (c1-256)] : 0.f);
                }
                wA[ia][g] = va; wB[ia][g] = vb;
            }
        }
        int aw = (a_lo < 4) ? a_lo : 4;   // P[t&3] freed by UF chain at t-4
        for (int t = 0; t < TDEC; t++) {
            int s = t - aw;
            if (s >= 0) {
                for (;;) {
                    int p = 1;
                    if (tid < NU2) p = (SCLD(&UF[tid]) >= s+1);
                    if (__syncthreads_count(p) == 512) break;
                    __builtin_amdgcn_s_sleep(1);
                }
            }
            float a0[16], a1[16];
            #pragma unroll
            for (int i = 0; i < 16; i++) { a0[i] = 0.f; a1[i] = 0.f; }
            for (int ia = 0; ia < n_ages; ia++) {
                int a = a_lo + ia;
                if (ia) __syncthreads();
                {   // batched stage of u_{t-a} (row-major) -> transposed LDS
                    const float* src = ws + OFF_U + (t + 17 - a)*5376;
                    float r[11];
                    #pragma unroll
                    for (int j = 0; j < 10; j++) r[j] = SCLD(&src[tid + j*512]);
                    if (tid < 256) r[10] = SCLD(&src[tid + 5120]);
                    #pragma unroll
                    for (int j = 0; j < 10; j++) {
                        int idx = tid + j*512;
                        int b = idx/336, d = idx - 336*b;
                        ulds[d*20 + b] = r[j];
                    }
                    if (tid < 256) {
                        int idx = tid + 5120;
                        int b = idx/336, d = idx - 336*b;
                        ulds[d*20 + b] = r[10];
                    }
                }
                __syncthreads();
                #pragma unroll
                for (int g = 0; g < 21; g++) {
                    int base = (kq*21 + g)*20;
                    float4 u0 = *(const float4*)&ulds[base];
                    float4 u1 = *(const float4*)&ulds[base+4];
                    float4 u2 = *(const float4*)&ulds[base+8];
                    float4 u3 = *(const float4*)&ulds[base+12];
                    float wa = wA[ia][g], wb = wB[ia][g];
                    a0[0]=fmaf(wa,u0.x,a0[0]);  a1[0]=fmaf(wb,u0.x,a1[0]);
                    a0[1]=fmaf(wa,u0.y,a0[1]);  a1[1]=fmaf(wb,u0.y,a1[1]);
                    a0[2]=fmaf(wa,u0.z,a0[2]);  a1[2]=fmaf(wb,u0.z,a1[2]);
                    a0[3]=fmaf(wa,u0.w,a0[3]);  a1[3]=fmaf(wb,u0.w,a1[3]);
                    a0[4]=fmaf(wa,u1.x,a0[4]);  a1[4]=fmaf(wb,u1.x,a1[4]);
                    a0[5]=fmaf(wa,u1.y,a0[5]);  a1[5]=fmaf(wb,u1.y,a1[5]);
                    a0[6]=fmaf(wa,u1.z,a0[6]);  a1[6]=fmaf(wb,u1.z,a1[6]);
                    a0[7]=fmaf(wa,u1.w,a0[7]);  a1[7]=fmaf(wb,u1.w,a1[7]);
                    a0[8]=fmaf(wa,u2.x,a0[8]);  a1[8]=fmaf(wb,u2.x,a1[8]);
                    a0[9]=fmaf(wa,u2.y,a0[9]);  a1[9]=fmaf(wb,u2.y,a1[9]);
                    a0[10]=fmaf(wa,u2.z,a0[10]); a1[10]=fmaf(wb,u2.z,a1[10]);
                    a0[11]=fmaf(wa,u2.w,a0[11]); a1[11]=fmaf(wb,u2.w,a1[11]);
                    a0[12]=fmaf(wa,u3.x,a0[12]); a1[12]=fmaf(wb,u3.x,a1[12]);
                    a0[13]=fmaf(wa,u3.y,a0[13]); a1[13]=fmaf(wb,u3.y,a1[13]);
                    a0[14]=fmaf(wa,u3.z,a0[14]); a1[14]=fmaf(wb,u3.z,a1[14]);
                    a0[15]=fmaf(wa,u3.w,a0[15]); a1[15]=fmaf(wb,u3.w,a1[15]);
                }
            }
            if (kq < 8) {
                #pragma unroll
                for (int bb = 0; bb < 16; bb++) {
                    red[kq*1024 + bb*64 + cp]      = a0[bb];
                    red[kq*1024 + bb*64 + cp + 32] = a1[bb];
                }
            }
            __syncthreads();
            if (kq >= 8) {
                #pragma unroll
                for (int bb = 0; bb < 16; bb++) {
                    red[(kq-8)*1024 + bb*64 + cp]      += a0[bb];
                    red[(kq-8)*1024 + bb*64 + cp + 32] += a1[bb];
                }
            }
            __syncthreads();
            int par = t & 3;
            for (int oi = tid; oi < 1024; oi += 512) {
                float s_ = 0.f;
                #pragma unroll
                for (int q = 0; q < 8; q++) s_ += red[q*1024 + oi];
                int bb = oi >> 6, cl = oi & 63;
                __hip_atomic_fetch_add(
                    &ws[OFF_P + ((par*B + bb)*832) + ct*64 + cl], s_, RLX, AGT);
            }
            __syncthreads();
            if (tid == 0) SCST(&AF[bid], t + 1);
        }
    } else if (bid < NA + NT) {
        // ====== T-WORKER: h1[b][col] = relu(prime + sum_d top[b][d]*w1[d][col]) ==
        int f = bid - NA;
        float* w1T  = smem;            // [cl][336] = 10752
        float* tlds = smem + 10752;    // [b][340] = 5440 -> 16192 total
        for (int idx = tid; idx < 10752; idx += 512) {
            int d = idx >> 5, c = idx & 31;
            int col = f*32 + c;
            w1T[c*336 + d] = (col < BH) ? w1g[d*BH + col] : 0.f;
        }
        __syncthreads();
        int cl = tid >> 4, b = tid & 15;
        int col = f*32 + cl;
        bool val = col < BH;
        for (int t = 0; t < TDEC; t++) {
            for (;;) {
                int p = 1;
                if (tid < NC) p = (SCLD(&CF[tid]) >= t+1);
                if (__syncthreads_count(p) == 512) break;
                __builtin_amdgcn_s_sleep(1);
            }
            int par2 = t & 1;
            float prime = val ? SCLD(&ws[OFF_H + par2*9152 + b*572 + col]) : 0.f;
            {   // batched stage of top[par2] (row-major) -> [b][340] LDS
                const float* src = ws + OFF_TOP + par2*5376;
                float r[11];
                #pragma unroll
                for (int j = 0; j < 10; j++) r[j] = SCLD(&src[tid + j*512]);
                if (tid < 256) r[10] = SCLD(&src[tid + 5120]);
                #pragma unroll
                for (int j = 0; j < 10; j++) {
                    int idx = tid + j*512;
                    int bb = idx/336, d = idx - 336*bb;
                    tlds[bb*340 + d] = r[j];
                }
                if (tid < 256) {
                    int idx = tid + 5120;
                    int bb = idx/336, d = idx - 336*bb;
                    tlds[bb*340 + d] = r[10];
                }
            }
            __syncthreads();
            // single-accumulator serial over d (float4 in-order = bit-identical)
            float acc = 0.f;
            const float4* tp = (const float4*)&tlds[b*340];
            const float4* wp = (const float4*)&w1T[cl*336];
            #pragma unroll 8
            for (int q = 0; q < 84; q++) {
                float4 tv = tp[q], wv = wp[q];
                acc = fmaf(tv.x, wv.x, acc); acc = fmaf(tv.y, wv.y, acc);
                acc = fmaf(tv.z, wv.z, acc); acc = fmaf(tv.w, wv.w, acc);
            }
            if (val)
                SCST(&ws[OFF_H + par2*9152 + b*572 + col], fmaxf(prime + acc, 0.f));
            __syncthreads();
            if (tid == 0) SCST(&TF[f], t + 1);
        }
    } else if (bid < NA + NT + NU2) {
        // ====== U-WORKER: u[b][dd] = b2[dd] + sum_c h1[b][c]*w2T[dd][c] ======
        int ub = bid - (NA + NT);
        int dd0 = ub*12;
        float* w2L  = smem;            // 12*572 = 6864
        float* hlds = smem + 6864;     // [b][572] = 9152 -> 16016
        for (int idx = tid; idx < 6864; idx += 512)
            w2L[idx] = ws[OFF_W2T + dd0*572 + idx];
        __syncthreads();
        int ddl = tid >> 4, b = tid & 15;
        bool act = tid < 192;
        for (int t = 0; t < TDEC; t++) {
            for (;;) {
                int p = 1;
                if (tid < NT) p = (SCLD(&TF[tid]) >= t+1);
                if (__syncthreads_count(p) == 512) break;
                __builtin_amdgcn_s_sleep(1);
            }
            int par2 = t & 1;
            {   // batched stage of h1 (contiguous [b][572])
                const float* src = ws + OFF_H + par2*9152;
                float r[18];
                #pragma unroll
                for (int j = 0; j < 18; j++) {
                    int idx = tid + j*512;
                    r[j] = (idx < 9152) ? SCLD(&src[idx]) : 0.f;
                }
                #pragma unroll
                for (int j = 0; j < 18; j++) {
                    int idx = tid + j*512;
                    if (idx < 9152) hlds[idx] = r[j];
                }
            }
            __syncthreads();
            if (act) {
                // single-accumulator serial over c (float4 in-order chain)
                float v = bp_b2[dd0 + ddl];
                const float4* hp = (const float4*)&hlds[b*572];
                const float4* wp = (const float4*)&w2L[ddl*572];
                #pragma unroll 8
                for (int q = 0; q < 143; q++) {
                    float4 hh = hp[q], wv = wp[q];
                    v = fmaf(hh.x, wv.x, v); v = fmaf(hh.y, wv.y, v);
                    v = fmaf(hh.z, wv.z, v); v = fmaf(hh.w, wv.w, v);
                }
                SCST(&ws[OFF_U + ((t+17)*B + b)*BD + dd0 + ddl], v);
            }
            __syncthreads();
            if (tid == 0) SCST(&UF[ub], t + 1);
        }
    } else {
        // ====== CONSUMER (one per b): merge P + attention + publish ======
        int b = bid - (NA + NT + NU2);
        float* pqa    = smem;          // 832
        float* sc     = smem + 832;    // 128
        float* attn_s = smem + 960;    // 128
        float* ctx2   = smem + 1088;   // 512
        float* topv   = smem + 1600;   // 336
        float* avs    = smem + 1936;   // 256
        if (tid < 256) avs[tid] = att_v[tid];
        __syncthreads();
        for (int t = 0; t < TDEC; t++) {
            for (;;) {
                int p = 1;
                if (tid < NA) p = (SCLD(&AF[tid]) >= t+1);
                if (__syncthreads_count(p) == 512) break;
                __builtin_amdgcn_s_sleep(1);
            }
            int par3 = t & 3, par2 = t & 1;
            {   // merge P row, add biases, zero P
                float* Pb = ws + OFF_P + (par3*B + b)*832;
                int c0 = tid;
                float p0 = SCLD(&Pb[c0]);
                SCST(&Pb[c0], 0.f);
                pqa[c0] = p0 + (c0 < 256 ? att_bq[c0] : bp_b1[c0-256]);
                if (tid < 315) {
                    int c1 = tid + 512;
                    float p1 = SCLD(&Pb[c1]);
                    SCST(&Pb[c1], 0.f);
                    pqa[c1] = p1 + bp_b1[c1-256];
                }
            }
            __syncthreads();
            {   // scores
                int j = tid >> 2, hq = tid & 3;
                const float* par_ = ws + OFF_PA + (b*TENC + j)*HID + hq*64;
                const float* pqh = &pqa[hq*64];
                const float* avh = &avs[hq*64];
                float a = 0.f;
                #pragma unroll 8
                for (int h = 0; h < 64; h++) {
                    float x = pqh[h] + par_[h];
                    float e = __expf(2.f*x);
                    a += avh[h]*(1.f - 2.f/(e + 1.f));
                }
                a += __shfl_xor(a, 1);
                a += __shfl_xor(a, 2);
                if (hq == 0) sc[j] = a;
            }
            __syncthreads();
            if (tid < 64) {
                float s0 = sc[2*tid], s1 = sc[2*tid+1];
                float m = fmaxf(s0, s1);
                #pragma unroll
                for (int off = 1; off < 64; off <<= 1) m = fmaxf(m, __shfl_xor(m, off));
                float e0 = __expf(s0 - m), e1 = __expf(s1 - m);
                float ssum = e0 + e1;
                #pragma unroll
                for (int off = 1; off < 64; off <<= 1) ssum += __shfl_xor(ssum, off);
                float r = 1.f/ssum;
                attn_s[2*tid] = e0*r; attn_s[2*tid+1] = e1*r;
                attns[(b*TDEC + t)*TENC + 2*tid]   = e0*r;
                attns[(b*TDEC + t)*TENC + 2*tid+1] = e1*r;
            }
            __syncthreads();
            {   // ctx
                int i = tid & 255, jh = tid >> 8;
                const float* inp = inputs + (b*TENC + jh*64)*IND + i;
                float csum = 0.f;
                #pragma unroll 8
                for (int j = 0; j < 64; j++)
                    csum += attn_s[jh*64 + j]*inp[j*IND];
                ctx2[jh*256 + i] = csum;
            }
            __syncthreads();
            if (tid < 256) topv[tid] = ctx2[tid] + ctx2[256 + tid];
            else if (tid < BD) topv[tid] = ws[OFF_MEM + (t*B + b)*MD + (tid-256)];
            __syncthreads();
            // publish top (contiguous) + H prime (contiguous, incl bias) + pad
            if (tid < BD)
                SCST(&ws[OFF_TOP + par2*5376 + b*336 + tid], topv[tid]);
            SCST(&ws[OFF_H + par2*9152 + b*572 + tid], pqa[256 + tid]);
            if (tid < 59)
                SCST(&ws[OFF_H + par2*9152 + b*572 + 512 + tid], pqa[256 + 512 + tid]);
            if (tid == 0)
                SCST(&ws[OFF_H + par2*9152 + b*572 + 571], 0.f);
            __syncthreads();
            if (tid == 0) SCST(&CF[b], t + 1);
        }
    }
}

// Epilogue: out[b,t,o] = c_out[o] + sum_{l,d} u_{t-l}[b][d]*M[l][d][o]
__global__ __launch_bounds__(256) void k_q2(float* __restrict__ outs,
        const float* __restrict__ ws) {
    __shared__ __align__(16) float uL[41*340];
    int bid = blockIdx.x;
    int b = bid >> 5, r = bid & 31, th = r >> 3, oc = r & 7;
    int t0 = th*25, obase = oc*50;
    int tid = threadIdx.x;
    int s0 = t0 + 1;
    for (int idx = tid; idx < 41*336; idx += 256) {
        int rr = idx / 336, d = idx - 336*rr;
        uL[rr*340 + d] = ws[OFF_U + ((s0 + rr)*B + b)*BD + d];
    }
    __syncthreads();
    int o = tid % 50, tq = tid / 50;
    if (tq < 5) {
        float acc[5] = {0.f, 0.f, 0.f, 0.f, 0.f};
        for (int l = 0; l < LBUF; l++) {
            const float* Mp = ws + OFF_M + (l*BD)*OD + obase + o;
            const float* ub = &uL[(tq*5 + 16 - l)*340];
            for (int d4 = 0; d4 < 84; d4++) {
                int d = d4*4;
                float m0 = Mp[(d+0)*OD], m1 = Mp[(d+1)*OD];
                float m2 = Mp[(d+2)*OD], m3 = Mp[(d+3)*OD];
                #pragma unroll
                for (int i = 0; i < 5; i++) {
                    float4 u4 = *(const float4*)&ub[i*340 + d];
                    acc[i] = fmaf(u4.x, m0, acc[i]);
                    acc[i] = fmaf(u4.y, m1, acc[i]);
                    acc[i] = fmaf(u4.z, m2, acc[i]);
                    acc[i] = fmaf(u4.w, m3, acc[i]);
                }
            }
        }
        float co = ws[OFF_CO + obase + o];
        #pragma unroll
        for (int i = 0; i < 5; i++) {
            int t = t0 + tq*5 + i;
            outs[(b*TDEC + t)*OD + obase + o] = acc[i] + co;
        }
    }
}

extern "C" void kernel_launch(void* const* d_in, const int* in_sizes, int n_in,
                              void* d_out, int out_size, void* d_ws, size_t ws_size,
                              hipStream_t stream) {
    const float* inputs  = (const float*)d_in[0];
    const float* targets = (const float*)d_in[1];
    const float* mp_w1   = (const float*)d_in[2];
    const float* mp_b1   = (const float*)d_in[3];
    const float* mp_w2   = (const float*)d_in[4];
    const float* mp_b2   = (const float*)d_in[5];
    const float* bp_w1   = (const float*)d_in[6];
    const float* bp_b1   = (const float*)d_in[7];
    const float* bp_w2   = (const float*)d_in[8];
    const float* bp_b2   = (const float*)d_in[9];
    const float* att_wq  = (const float*)d_in[10];
    const float* att_bq  = (const float*)d_in[11];
    const float* att_wa  = (const float*)d_in[12];
    const float* att_ba  = (const float*)d_in[13];
    const float* att_v   = (const float*)d_in[14];
    const float* scale_w = (const float*)d_in[15];
    const float* scale_b = (const float*)d_in[16];
    const float* out_w   = (const float*)d_in[17];
    const float* out_b   = (const float*)d_in[18];
    float* ws = (float*)d_ws;
    float* outs = (float*)d_out;
    float* attns = outs + B*TDEC*OD;

    k_init<<<569, 256, 0, stream>>>(ws);
    k_pa  <<<B*TENC, 256, 0, stream>>>(inputs, att_wa, att_ba, ws);
    k_mem <<<TDEC*B, 128, 0, stream>>>(targets, mp_w1, mp_b1, mp_w2, mp_b2, ws);
    k_M   <<<17*14, 256, 0, stream>>>(scale_w, out_w, ws);
    k_cout<<<17, 256, 0, stream>>>(scale_b, out_w, out_b, ws);
    k_tr  <<<(BD*572 + 255)/256, 256, 0, stream>>>(bp_w2, ws);
    k_scan<<<NBLK, 512, 0, stream>>>(inputs, att_wq, bp_w1, att_bq, bp_b1,
                                     bp_b2, att_v, ws, attns);
    k_q2  <<<512, 256, 0, stream>>>(outs, ws);
}